// Round 3
// baseline (5827.303 us; speedup 1.0000x reference)
//
#include <hip/hip_runtime.h>
#include <hip/hip_bf16.h>
#include <hip/hip_fp16.h>

// GCN: h1 = relu(gcn(x,W1,b1)); h2 = relu(gcn(h1,W2,b2));
// pooled = segment_sum(h2, batch); out = sigmoid(pooled@Wc + bc)
// R13 NEUTRAL: 4x fewer gather instrs, dur 120->118. Not issue-bound.
// R14 NEUTRAL: per-node source-sort didn't move FETCH (32-edge lists too
//   sparse to align sweeps). Conclusion: post-L2 path saturated at
//   ~380MB/118us; only lever is post-L2 BYTES.
// R15: edge-centric agg. Bins of 128 targets; bin_sort counting-sorts each
//   bin's ~4100 edges by source band (row>>9) + injects self-loops + dinv.
//   agg2 per (bin, feat-half): 32KB LDS fp32 acc, 4 blocks/CU -> ALL 782
//   blocks resident -> synchronized dense sweep of a 12.8MB Y half-plane;
//   each XCD fetches each line ~once. readlane-broadcast meta (SGPR row/w),
//   64-lane 128B row-half gathers, ds_add_f32 acc (2-way bank = free).
//   Pred: agg2 FETCH ~130MB, dur 30-45us x4 (vs 118x2); absmax improves
//   (fp32 acc); total ~420-470.

#define FEAT 128
#define OUTC 64
#define NB_SHIFT 7
#define BINSZ 128      // targets per bin
#define CAP 4608       // per-bin edge capacity (mean 4092, +8 sigma)
#define CAP2 (CAP + BINSZ)  // sorted list incl self-loops
#define NKEY 256       // source-sort buckets (row>>9 < 196)
#define KSHIFT 9
#define TILE_A 8192    // edges per phase-A block
#define CNT_STRIDE 16  // binCnt padding: one counter per 64B line
#define LDW 136        // padded W^T row stride (halves)

typedef _Float16 half8 __attribute__((ext_vector_type(8)));
typedef float    f32x4 __attribute__((ext_vector_type(4)));

// ---- Phase A: bin edges by col>>7 -----------------------------------------
__global__ __launch_bounds__(256) void bin_edges(const int* __restrict__ ei,
                                                 const float* __restrict__ ew,
                                                 int* __restrict__ binCnt,
                                                 int2* __restrict__ binned,
                                                 int E, int nbins) {
    __shared__ int hist[1024];
    __shared__ int base[1024];
    int tid = threadIdx.x;
    int e0 = blockIdx.x * TILE_A;
    for (int i = tid; i < nbins; i += 256) hist[i] = 0;
    __syncthreads();
    for (int i = 0; i < TILE_A; i += 256) {
        int e = e0 + i + tid;
        if (e < E) atomicAdd(&hist[ei[E + e] >> NB_SHIFT], 1);
    }
    __syncthreads();
    for (int i = tid; i < nbins; i += 256) {
        int h = hist[i];
        base[i] = (h > 0) ? atomicAdd(&binCnt[i * CNT_STRIDE], h) : 0;
        hist[i] = 0;
    }
    __syncthreads();
    for (int i = 0; i < TILE_A; i += 256) {
        int e = e0 + i + tid;
        if (e < E) {
            int col = ei[E + e];
            int row = ei[e];
            float w = ew[e];
            int b  = col >> NB_SHIFT;
            int lp = atomicAdd(&hist[b], 1);
            int pos = base[b] + lp;
            if (pos < CAP) {
                int cl = col & (BINSZ - 1);
                binned[(size_t)b * CAP + pos] = make_int2((cl << 24) | row, __float_as_int(w));
            }
        }
    }
}

// ---- Phase B: counting-sort bin by source band; inject self-loops; dinv ----
__global__ __launch_bounds__(256) void bin_sort(const int2* __restrict__ binned,
                                                const int* __restrict__ binCnt,
                                                int2* __restrict__ binned2,
                                                float* __restrict__ dinv, int N) {
    extern __shared__ int2 sE[];           // CAP2 entries = 37888 B dynamic
    __shared__ float dsum[BINSZ];
    __shared__ int kh[NKEY], kb[NKEY], ksc[NKEY];
    int tid = threadIdx.x, b = blockIdx.x;
    int node0 = b << NB_SHIFT;
    int nnode = min(BINSZ, N - node0);
    if (tid < BINSZ) dsum[tid] = 0.f;
    kh[tid] = 0;
    __syncthreads();
    int ne = min(binCnt[b * CNT_STRIDE], CAP);
    const int2* src = binned + (size_t)b * CAP;
    // pass 1: band histogram + degree sums (edges)
    for (int i = tid; i < ne; i += 256) {
        int2 m = src[i];
        atomicAdd(&kh[(m.x & 0xFFFFFF) >> KSHIFT], 1);
        atomicAdd(&dsum[((unsigned)m.x) >> 24], __int_as_float(m.y));
    }
    // self-loop contributions (weight 1.0)
    if (tid < nnode) {
        atomicAdd(&kh[(node0 + tid) >> KSHIFT], 1);
        atomicAdd(&dsum[tid], 1.0f);
    }
    __syncthreads();
    // exclusive scan kh -> kb (Hillis-Steele over NKEY==256==blockDim)
    int v = kh[tid];
    ksc[tid] = v;
    __syncthreads();
    for (int off = 1; off < NKEY; off <<= 1) {
        int t = (tid >= off) ? ksc[tid - off] : 0;
        __syncthreads();
        ksc[tid] += t;
        __syncthreads();
    }
    kb[tid] = ksc[tid] - v;
    kh[tid] = 0;
    __syncthreads();
    // pass 2: scatter into LDS at band-sorted positions
    for (int i = tid; i < ne; i += 256) {
        int2 m = src[i];
        int k = (m.x & 0xFFFFFF) >> KSHIFT;
        sE[kb[k] + atomicAdd(&kh[k], 1)] = m;
    }
    if (tid < nnode) {
        int node = node0 + tid;
        int k = node >> KSHIFT;
        sE[kb[k] + atomicAdd(&kh[k], 1)] = make_int2((tid << 24) | node, __float_as_int(1.0f));
    }
    __syncthreads();
    // pass 3: stream sorted list to global
    int tot = ne + nnode;
    int2* dst = binned2 + (size_t)b * CAP2;
    for (int i = tid; i < tot; i += 256) dst[i] = sE[i];
    if (tid < nnode) dinv[node0 + tid] = rsqrtf(dsum[tid]);
}

// ---- one-time padded W^T fp16 prep (row stride LDW) ------------------------
__global__ void wt_prep(const float* __restrict__ W, _Float16* __restrict__ Wt) {
    int i = blockIdx.x * 256 + threadIdx.x;   // i < 16384
    int n = i >> 7, k = i & 127;
    Wt[(size_t)n * LDW + k] = (_Float16)W[(size_t)k * FEAT + n];
}

// ---- Y(fp16) = dinv[:,None]*(X @ W) via MFMA; B staged flat into LDS -------
__global__ __launch_bounds__(256) void gemm_mfma(const float* __restrict__ X,
                                                 const _Float16* __restrict__ Wt,
                                                 const float* __restrict__ dinv,
                                                 __half* __restrict__ Y, int N) {
    __shared__ _Float16 sWt[FEAT * LDW];   // 34816 B
    int tid  = threadIdx.x;
    int row0 = blockIdx.x * 128;
    {
        const int4* src = (const int4*)Wt;
        int4* dst = (int4*)sWt;
        for (int i = tid; i < (FEAT * LDW) / 8; i += 256) dst[i] = src[i];
    }
    __syncthreads();

    int wave = tid >> 6;
    int lane = tid & 63;
    int m    = lane & 15;
    int quad = lane >> 4;

    f32x4 acc[2][8];
    #pragma unroll
    for (int rt = 0; rt < 2; ++rt)
        #pragma unroll
        for (int ct = 0; ct < 8; ++ct)
            acc[rt][ct] = (f32x4){0.f, 0.f, 0.f, 0.f};

    int rowA[2];
    rowA[0] = min(row0 + wave * 32 + m, N - 1);
    rowA[1] = min(row0 + wave * 32 + 16 + m, N - 1);

    #pragma unroll
    for (int kt = 0; kt < 4; ++kt) {
        int k0 = kt * 32;
        half8 a[2];
        #pragma unroll
        for (int rt = 0; rt < 2; ++rt) {
            const float4* p = (const float4*)(X + (size_t)rowA[rt] * FEAT + k0 + quad * 8);
            float4 f0 = p[0], f1 = p[1];
            half8 h;
            h[0] = (_Float16)f0.x; h[1] = (_Float16)f0.y;
            h[2] = (_Float16)f0.z; h[3] = (_Float16)f0.w;
            h[4] = (_Float16)f1.x; h[5] = (_Float16)f1.y;
            h[6] = (_Float16)f1.z; h[7] = (_Float16)f1.w;
            a[rt] = h;
        }
        #pragma unroll
        for (int ct = 0; ct < 8; ++ct) {
            half8 b = *(const half8*)&sWt[(ct * 16 + m) * LDW + k0 + quad * 8];
            acc[0][ct] = __builtin_amdgcn_mfma_f32_16x16x32_f16(a[0], b, acc[0][ct], 0, 0, 0);
            acc[1][ct] = __builtin_amdgcn_mfma_f32_16x16x32_f16(a[1], b, acc[1][ct], 0, 0, 0);
        }
    }

    #pragma unroll
    for (int rt = 0; rt < 2; ++rt) {
        int lr0 = wave * 32 + rt * 16 + quad * 4;
        #pragma unroll
        for (int r = 0; r < 4; ++r) {
            int gr = row0 + lr0 + r;
            if (gr < N) {
                float d = dinv[gr];
                #pragma unroll
                for (int ct = 0; ct < 8; ++ct)
                    Y[(size_t)gr * FEAT + ct * 16 + m] = __float2half(d * acc[rt][ct][r]);
            }
        }
    }
}

// ---- edge-centric aggregation: bin-block LDS fp32 acc, source-sorted sweep -
// Block = (bin b, feat-half hsel). sAcc[128 targets][64 feats] fp32 = 32KB
// -> 4 blocks/CU, all 782 blocks resident: one synchronized sweep through the
// 12.8MB Y half-plane. Per 64-edge chunk: lane-parallel meta load, readlane
// broadcast (row/w/cl in SGPRs), 64-lane 128B half-row gather, ds_add_f32.
__global__ __launch_bounds__(256) void agg2(const __half* __restrict__ Y,
                                            const int2* __restrict__ binned2,
                                            const int* __restrict__ binCnt,
                                            const float* __restrict__ dinv,
                                            const float* __restrict__ bias,
                                            float* __restrict__ H, int N, int hsel) {
    __shared__ float sAcc[BINSZ * 64];   // 32 KB
    int tid = threadIdx.x, b = blockIdx.x;
    int node0 = b << NB_SHIFT;
    int nnode = min(BINSZ, N - node0);
    for (int i = tid; i < BINSZ * 64; i += 256) sAcc[i] = 0.f;
    __syncthreads();
    int ne = min(binCnt[b * CNT_STRIDE], CAP) + nnode;  // incl. self-loops
    const int2* src = binned2 + (size_t)b * CAP2;
    int wave = tid >> 6, lane = tid & 63;
    const __half* Ycol = Y + hsel * 64 + lane;          // this lane's feat col
    int e0 = wave * 64;
    for (; e0 + 64 <= ne; e0 += 256) {
        int2 mm = src[e0 + lane];
        #pragma unroll 16
        for (int i = 0; i < 64; ++i) {
            int mx = __builtin_amdgcn_readlane(mm.x, i);
            int mw = __builtin_amdgcn_readlane(mm.y, i);
            int row = mx & 0xFFFFFF;
            int cl  = ((unsigned)mx) >> 24;
            float w = __int_as_float(mw);
            float val = __half2float(Ycol[(size_t)row * FEAT]);
            atomicAdd(&sAcc[cl * 64 + lane], w * val);
        }
    }
    if (e0 < ne) {                                      // straddling wave tail
        int nloc = ne - e0;
        int2 mm = (e0 + lane < ne) ? src[e0 + lane] : make_int2(0, 0);
        for (int i = 0; i < nloc; ++i) {
            int mx = __builtin_amdgcn_readlane(mm.x, i);
            int mw = __builtin_amdgcn_readlane(mm.y, i);
            int row = mx & 0xFFFFFF;
            int cl  = ((unsigned)mx) >> 24;
            float w = __int_as_float(mw);
            float val = __half2float(Ycol[(size_t)row * FEAT]);
            atomicAdd(&sAcc[cl * 64 + lane], w * val);
        }
    }
    __syncthreads();
    for (int i = tid; i < nnode * 64; i += 256) {
        int t = i >> 6, f = i & 63;
        int node = node0 + t;
        float o = dinv[node] * sAcc[t * 64 + f] + bias[hsel * 64 + f];
        H[(size_t)node * FEAT + hsel * 64 + f] = fmaxf(o, 0.f);
    }
}

// ---- pooling (batch is sorted): running accumulate, flush on graph change --
__global__ void pool_kernel(const float* __restrict__ H, const int* __restrict__ batch,
                            float* __restrict__ pooled, int N, int chunk) {
    int f  = threadIdx.x;
    int n0 = blockIdx.x * chunk;
    if (n0 >= N) return;
    int n1 = min(n0 + chunk, N);
    float acc = 0.f;
    int cur = batch[n0];
    for (int n = n0; n < n1; ++n) {
        int g = batch[n];
        if (g != cur) {
            atomicAdd(&pooled[cur * FEAT + f], acc);
            acc = 0.f;
            cur = g;
        }
        acc += H[(size_t)n * FEAT + f];
    }
    atomicAdd(&pooled[cur * FEAT + f], acc);
}

// ---- classifier ------------------------------------------------------------
__global__ void classify_kernel(const float* __restrict__ pooled, const float* __restrict__ Wc,
                                const float* __restrict__ bc, float* __restrict__ out) {
    int g = blockIdx.x;
    int c = threadIdx.x;
    float acc = bc[c];
    const float* pr = pooled + g * FEAT;
    for (int k = 0; k < FEAT; ++k) acc += pr[k] * Wc[k * OUTC + c];
    out[g * OUTC + c] = 1.0f / (1.0f + expf(-acc));
}

extern "C" void kernel_launch(void* const* d_in, const int* in_sizes, int n_in,
                              void* d_out, int out_size, void* d_ws, size_t ws_size,
                              hipStream_t stream) {
    const float* x     = (const float*)d_in[0];
    const int*   ei    = (const int*)d_in[1];
    const float* ew    = (const float*)d_in[2];
    const int*   batch = (const int*)d_in[3];
    const float* W1    = (const float*)d_in[4];
    const float* b1    = (const float*)d_in[5];
    const float* W2    = (const float*)d_in[6];
    const float* b2    = (const float*)d_in[7];
    const float* Wc    = (const float*)d_in[8];
    const float* bc    = (const float*)d_in[9];
    float* out = (float*)d_out;

    const int N = in_sizes[0] / FEAT;
    const int E = in_sizes[2];
    const int G = out_size / OUTC;
    const int nbins = (N + BINSZ - 1) / BINSZ;

    char* w = (char*)d_ws;
    size_t off = 0;
    auto alloc = [&](size_t bytes) {
        void* p = w + off;
        off = (off + bytes + 255) & ~(size_t)255;
        return p;
    };
    float*     dinv    = (float*)alloc((size_t)N * 4);
    int*       binCnt  = (int*)alloc((size_t)nbins * CNT_STRIDE * 4);  // line-padded
    int2*      binned  = (int2*)alloc((size_t)nbins * CAP * 8);   // ~28.8 MB
    int2*      binned2 = (int2*)alloc((size_t)nbins * CAP2 * 8);  // ~29.6 MB sorted
    __half*    bufY    = (__half*)alloc((size_t)N * FEAT * 2);    // fp16 Y
    float*     bufH    = (float*)alloc((size_t)N * FEAT * 4);     // fp32 h
    float*     pooled  = (float*)alloc((size_t)G * FEAT * 4);
    _Float16*  wt1     = (_Float16*)alloc((size_t)FEAT * LDW * 2);
    _Float16*  wt2     = (_Float16*)alloc((size_t)FEAT * LDW * 2);
    (void)ws_size;

    hipMemsetAsync(binCnt, 0, (size_t)nbins * CNT_STRIDE * 4, stream);
    hipMemsetAsync(pooled, 0, (size_t)G * FEAT * 4, stream);

    bin_edges<<<(E + TILE_A - 1) / TILE_A, 256, 0, stream>>>(ei, ew, binCnt, binned, E, nbins);
    bin_sort<<<nbins, 256, (size_t)CAP2 * sizeof(int2), stream>>>(binned, binCnt, binned2, dinv, N);
    wt_prep<<<64, 256, 0, stream>>>(W1, wt1);
    wt_prep<<<64, 256, 0, stream>>>(W2, wt2);

    const int gemm_blocks = (N + 127) / 128;

    gemm_mfma<<<gemm_blocks, 256, 0, stream>>>(x, wt1, dinv, bufY, N);
    agg2<<<nbins, 256, 0, stream>>>(bufY, binned2, binCnt, dinv, b1, bufH, N, 0);
    agg2<<<nbins, 256, 0, stream>>>(bufY, binned2, binCnt, dinv, b1, bufH, N, 1);
    gemm_mfma<<<gemm_blocks, 256, 0, stream>>>(bufH, wt2, dinv, bufY, N);
    agg2<<<nbins, 256, 0, stream>>>(bufY, binned2, binCnt, dinv, b2, bufH, N, 0);
    agg2<<<nbins, 256, 0, stream>>>(bufY, binned2, binCnt, dinv, b2, bufH, N, 1);

    const int chunk = 128;
    pool_kernel<<<(N + chunk - 1) / chunk, FEAT, 0, stream>>>(bufH, batch, pooled, N, chunk);
    classify_kernel<<<G, OUTC, 0, stream>>>(pooled, Wc, bc, out);
}